// Round 3
// baseline (3628.406 us; speedup 1.0000x reference)
//
#include <hip/hip_runtime.h>

#define N_TOK 131072
#define KC    1024
#define DIM   256
#define TM    64
#define TNC   128          // codes per chunk (8 per thread x 16 tx lanes)
#define LDST  260          // zA row stride (floats): 16B-aligned, breaks power-of-2 bank strides

// ws layout:
// [0 .. 16K)           double partials[2048]
// [16K .. 16K+512K)    int best_idx[N_TOK]
// [16K+512K .. +4K)    float cnorm[KC]

// One wave per code: coalesced 1KB read, f64 square-sum, butterfly reduce.
__global__ void vq_cnorm(const float* __restrict__ cb, float* __restrict__ cnorm) {
    int w    = (blockIdx.x * 256 + threadIdx.x) >> 6;   // global wave id = code
    int lane = threadIdx.x & 63;
    float4 v = ((const float4*)cb)[(size_t)w * 64 + lane];
    double s = 0.0;
    s = fma((double)v.x, (double)v.x, s);
    s = fma((double)v.y, (double)v.y, s);
    s = fma((double)v.z, (double)v.z, s);
    s = fma((double)v.w, (double)v.w, s);
    #pragma unroll
    for (int off = 32; off > 0; off >>= 1) s += __shfl_xor(s, off);
    if (lane == 0) cnorm[w] = (float)s;   // ~1e-12 from np's f32 pairwise sum; f32 grid is 3e-5
}

// Distance GEMM, numpy-f32-faithful:
//   e[n,k] : strict sequential-k f32 FMA (d=0..255 in order, x,y,z,w within float4)
//   d[n,k] = fl( fl(zz_n + cc_k) - fl(2*e) )
//   argmin : lowest index wins on exact f32 ties
// Block: 256 thr = 16(tx: codes) x 16(ty: rows); thread tile 4 rows x 8 codes.
// z tile in LDS (67 KB -> 2 blocks/CU); codebook read direct from global (L1/L2-resident).
__global__ __launch_bounds__(256, 2)
void vq_scores(const float* __restrict__ z, const float* __restrict__ cb,
               const float* __restrict__ cnorm, int* __restrict__ best_idx,
               float* __restrict__ out_idx)
{
    __shared__ float zA[TM][LDST];
    __shared__ float zzf[TM];
    const int tid = threadIdx.x;
    const int tx = tid & 15;
    const int ty = tid >> 4;
    const int row0 = blockIdx.x * TM;

    // stage z tile: 64 rows x 256 f32, coalesced float4, conflict-free
    {
        const float4* zg = (const float4*)(z + (size_t)row0 * DIM);
        #pragma unroll
        for (int t = 0; t < 16; ++t) {
            int f = tid + t * 256;
            int r = f >> 6;
            int c = f & 63;
            *(float4*)&zA[r][c * 4] = zg[(size_t)r * 64 + c];
        }
    }
    __syncthreads();
    if (tid < TM) {  // zz per row, f64 (uniform row shift -> order-irrelevant after f32 round)
        double s = 0.0;
        for (int d = 0; d < DIM; ++d) { double v = (double)zA[tid][d]; s = fma(v, v, s); }
        zzf[tid] = (float)s;
    }
    __syncthreads();

    float rm1[4]; int ridx[4];
    #pragma unroll
    for (int i = 0; i < 4; ++i) { rm1[i] = 3.0e38f; ridx[i] = 0; }

    for (int nc = 0; nc < KC / TNC; ++nc) {
        float acc[4][8];
        #pragma unroll
        for (int i = 0; i < 4; ++i)
            #pragma unroll
            for (int j = 0; j < 8; ++j) acc[i][j] = 0.0f;

        const float* cbase = cb + (size_t)(nc * TNC + tx) * DIM;

        // strict sequential k: d4 ascending, x,y,z,w ascending => k = 0..255 in order
        #pragma unroll 4
        for (int d4 = 0; d4 < 64; ++d4) {
            float4 zr[4], cr[8];
            #pragma unroll
            for (int i = 0; i < 4; ++i) zr[i] = *(const float4*)&zA[ty * 4 + i][d4 * 4];
            #pragma unroll
            for (int j = 0; j < 8; ++j) cr[j] = *(const float4*)(cbase + j * 16 * DIM + d4 * 4);
            #pragma unroll
            for (int i = 0; i < 4; ++i)
                #pragma unroll
                for (int j = 0; j < 8; ++j) {
                    acc[i][j] = fmaf(zr[i].x, cr[j].x, acc[i][j]);
                    acc[i][j] = fmaf(zr[i].y, cr[j].y, acc[i][j]);
                    acc[i][j] = fmaf(zr[i].z, cr[j].z, acc[i][j]);
                    acc[i][j] = fmaf(zr[i].w, cr[j].w, acc[i][j]);
                }
        }

        float cn[8];
        #pragma unroll
        for (int j = 0; j < 8; ++j) cn[j] = cnorm[nc * TNC + j * 16 + tx];

        #pragma unroll
        for (int i = 0; i < 4; ++i) {
            float zz = zzf[ty * 4 + i];
            float c1 = 3.0e38f; int ci = 0;
            #pragma unroll
            for (int j = 0; j < 8; ++j) {            // j ascending -> strict '<' keeps lowest code
                int code = nc * TNC + j * 16 + tx;
                float A  = zz + cn[j];               // fl(zz + cc)
                float dq = A - 2.0f * acc[i][j];     // fl(A - fl(2e)); 2e exact
                if (dq < c1) { c1 = dq; ci = code; }
            }
            #pragma unroll
            for (int off = 1; off < 16; off <<= 1) { // merge across 16 tx lanes, lowest idx on tie
                float o1 = __shfl_xor(c1, off, 16);
                int  oi = __shfl_xor(ci, off, 16);
                if (o1 < c1 || (o1 == c1 && oi < ci)) { c1 = o1; ci = oi; }
            }
            if (c1 < rm1[i] || (c1 == rm1[i] && ci < ridx[i])) { rm1[i] = c1; ridx[i] = ci; }
        }
    }

    if (tx == 0) {
        #pragma unroll
        for (int i = 0; i < 4; ++i) {
            int row = row0 + ty * 4 + i;
            best_idx[row] = ridx[i];
            out_idx[row]  = (float)ridx[i];
        }
    }
}

// z_st = fl(z + fl(z_q - z)) (reference op order); per-block f64 loss partial (no global atomics).
__global__ void vq_outputs(const float* __restrict__ z, const float* __restrict__ cb,
                           const int* __restrict__ best_idx, float* __restrict__ out,
                           double* __restrict__ partials)
{
    __shared__ double sred[4];
    size_t g = (size_t)blockIdx.x * 256 + threadIdx.x;   // float4 index
    int row = (int)(g >> 6);
    int c4  = (int)(g & 63);
    float4 zv = ((const float4*)z)[g];
    int idx = best_idx[row];
    float4 cv = ((const float4*)(cb + (size_t)idx * DIM))[c4];
    float4 o;
    o.x = zv.x + (cv.x - zv.x);
    o.y = zv.y + (cv.y - zv.y);
    o.z = zv.z + (cv.z - zv.z);
    o.w = zv.w + (cv.w - zv.w);
    ((float4*)out)[g] = o;

    float dx = zv.x - cv.x, dy = zv.y - cv.y, dz = zv.z - cv.z, dw = zv.w - cv.w;
    double ls = (double)dx * dx + (double)dy * dy + (double)dz * dz + (double)dw * dw;
    #pragma unroll
    for (int off = 32; off > 0; off >>= 1) ls += __shfl_down(ls, off);
    if ((threadIdx.x & 63) == 0) sred[threadIdx.x >> 6] = ls;
    __syncthreads();
    if (threadIdx.x == 0) partials[blockIdx.x] = (sred[0] + sred[1]) + (sred[2] + sred[3]);
}

__global__ void vq_loss_final(const double* __restrict__ partials, float* __restrict__ out_loss) {
    __shared__ double s[256];
    const int tid = threadIdx.x;
    double a = 0.0;
    for (int i = tid; i < 2048; i += 256) a += partials[i];
    s[tid] = a;
    __syncthreads();
    for (int sft = 128; sft > 0; sft >>= 1) {
        if (tid < sft) s[tid] += s[tid + sft];
        __syncthreads();
    }
    if (tid == 0) {
        float mean = (float)(s[0] / (double)(N_TOK * (size_t)DIM));
        out_loss[0] = 0.25f * mean + mean;   // commit + codebook, reference op order
    }
}

extern "C" void kernel_launch(void* const* d_in, const int* in_sizes, int n_in,
                              void* d_out, int out_size, void* d_ws, size_t ws_size,
                              hipStream_t stream) {
    const float* z  = (const float*)d_in[0];
    const float* cb = (const float*)d_in[1];
    float* out = (float*)d_out;
    char* ws = (char*)d_ws;

    double* partials = (double*)(ws);
    int*    best_idx = (int*)(ws + 16384);
    float*  cnorm    = (float*)(ws + 16384 + (size_t)N_TOK * 4);

    float* out_idx  = out + (size_t)N_TOK * DIM;
    float* out_loss = out_idx + N_TOK;

    vq_cnorm<<<KC / 4, 256, 0, stream>>>(cb, cnorm);
    vq_scores<<<N_TOK / TM, 256, 0, stream>>>(z, cb, cnorm, best_idx, out_idx);
    vq_outputs<<<(N_TOK * (DIM / 4)) / 256, 256, 0, stream>>>(z, cb, best_idx, out, partials);
    vq_loss_final<<<1, 256, 0, stream>>>(partials, out + (size_t)N_TOK * DIM + N_TOK);
}

// Round 4
// 1155.239 us; speedup vs baseline: 3.1408x; 3.1408x over previous
//
#include <hip/hip_runtime.h>

#define N_TOK 131072
#define KC    1024
#define DIM   256

#define TM    64            // rows per block
#define TN    256           // codes per chunk
#define NCH   (KC / TN)     // 4 chunks
#define SLICE 4             // d4-steps staged per slice
#define NSL   ((DIM/4) / SLICE)  // 16 slices per chunk
#define NR    8             // rows per thread   (ty: 8 groups)
#define NC    8             // codes per thread  (tx: 32 lanes)

// ws layout: [0,16K) double partials[2048] ; [16K,20K) float cnorm[KC] ;
//            [20K, 20K+512K) float zzg[N_TOK] ; [544768, +1MB) float cbT (optional)

// One wave per row: coalesced 1KB read, f64 square-sum, butterfly reduce.
__global__ void vq_znorm(const float* __restrict__ z, float* __restrict__ zzg) {
    int w    = (blockIdx.x * 256 + threadIdx.x) >> 6;
    int lane = threadIdx.x & 63;
    float4 v = ((const float4*)z)[(size_t)w * 64 + lane];
    double s = 0.0;
    s = fma((double)v.x, (double)v.x, s);
    s = fma((double)v.y, (double)v.y, s);
    s = fma((double)v.z, (double)v.z, s);
    s = fma((double)v.w, (double)v.w, s);
    #pragma unroll
    for (int off = 32; off > 0; off >>= 1) s += __shfl_xor(s, off);
    if (lane == 0) zzg[w] = (float)s;   // f64->f32: uniform per-row shift, argmin-invariant
}

__global__ void vq_cnorm(const float* __restrict__ cb, float* __restrict__ cnorm) {
    int w    = (blockIdx.x * 256 + threadIdx.x) >> 6;
    int lane = threadIdx.x & 63;
    float4 v = ((const float4*)cb)[(size_t)w * 64 + lane];
    double s = 0.0;
    s = fma((double)v.x, (double)v.x, s);
    s = fma((double)v.y, (double)v.y, s);
    s = fma((double)v.z, (double)v.z, s);
    s = fma((double)v.w, (double)v.w, s);
    #pragma unroll
    for (int off = 32; off > 0; off >>= 1) s += __shfl_xor(s, off);
    if (lane == 0) cnorm[w] = (float)s;
}

// cbT[d4][code][4] = cb[code][4*d4 .. 4*d4+4)  (coalesced writes, scattered L2 reads)
__global__ void vq_transpose(const float* __restrict__ cb, float* __restrict__ cbT) {
    int g = blockIdx.x * 256 + threadIdx.x;       // [0, 65536)
    int d4 = g >> 10, code = g & 1023;
    ((float4*)cbT)[g] = ((const float4*)cb)[(size_t)code * 64 + d4];
}

// Distance GEMM, numpy-f32-faithful. Per acc: strict sequential-k f32 FMA chain
// (slices ascending, d4 ascending, x,y,z,w) == k = 0..255 in memory order.
// d = fl( fl(zz + cc) - fl(2*e) ), argmin lowest-index-wins on f32 ties.
template<bool USE_T>
__global__ __launch_bounds__(256, 2)
void vq_scores(const float* __restrict__ z, const float* __restrict__ cb,
               const float* __restrict__ cbT, const float* __restrict__ cnorm,
               const float* __restrict__ zzg, float* __restrict__ out_idx)
{
    __shared__ float zA[TM][DIM];          // 64 KB, unpadded (reads are 2-way broadcast: free)
    __shared__ float cA[SLICE][TN][4];     // 16 KB  -> total exactly 80 KB, 2 blocks/CU
    const int tid = threadIdx.x;
    const int tx = tid & 31;
    const int ty = tid >> 5;
    const int row0 = blockIdx.x * TM;

    // stage z tile: 4096 float4, coalesced, conflict-free (one row per wave-instr)
    {
        const float4* zg = (const float4*)(z + (size_t)row0 * DIM);
        float4* zs = (float4*)&zA[0][0];
        #pragma unroll
        for (int t = 0; t < 16; ++t) zs[tid + t * 256] = zg[tid + t * 256];
    }

    // per-thread row norms (broadcast loads, L2-hot)
    float zzr[NR];
    #pragma unroll
    for (int i = 0; i < NR; ++i) zzr[i] = zzg[row0 + ty * NR + i];

    // preload slice 0 of chunk 0 into registers
    float4 rn[4];
    #pragma unroll
    for (int t = 0; t < 4; ++t) {
        if (USE_T) rn[t] = ((const float4*)cbT)[(size_t)t * KC + tid];
        else       rn[t] = ((const float4*)cb)[(size_t)tid * 64 + t];
    }

    float rm1[NR]; int ridx[NR];
    #pragma unroll
    for (int i = 0; i < NR; ++i) { rm1[i] = 3.0e38f; ridx[i] = 0; }

    #pragma unroll 1
    for (int nc = 0; nc < NCH; ++nc) {
        float acc[NR][NC];
        #pragma unroll
        for (int i = 0; i < NR; ++i)
            #pragma unroll
            for (int j = 0; j < NC; ++j) acc[i][j] = 0.0f;

        #pragma unroll 1
        for (int s = 0; s < NSL; ++s) {
            __syncthreads();                       // previous slice fully consumed (also covers zA stage)
            #pragma unroll
            for (int t = 0; t < 4; ++t) *(float4*)&cA[t][tid][0] = rn[t];
            __syncthreads();                       // slice ready

            {   // prefetch next slice into registers (hidden under compute below)
                int ns = s + 1, nn = nc;
                if (ns == NSL) { ns = 0; nn = nc + 1; }
                if (nn < NCH) {
                    #pragma unroll
                    for (int t = 0; t < 4; ++t) {
                        int d4 = ns * SLICE + t;
                        int code = nn * TN + tid;
                        if (USE_T) rn[t] = ((const float4*)cbT)[(size_t)d4 * KC + code];
                        else       rn[t] = ((const float4*)cb)[(size_t)code * 64 + d4];
                    }
                }
            }

            #pragma unroll
            for (int d4l = 0; d4l < SLICE; ++d4l) {
                const int d4 = s * SLICE + d4l;
                float4 zr[NR], cr[NC];
                #pragma unroll
                for (int i = 0; i < NR; ++i) zr[i] = *(const float4*)&zA[ty * NR + i][d4 * 4];
                #pragma unroll
                for (int j = 0; j < NC; ++j) cr[j] = *(const float4*)&cA[d4l][j * 32 + tx][0];
                #pragma unroll
                for (int i = 0; i < NR; ++i)
                    #pragma unroll
                    for (int j = 0; j < NC; ++j) {
                        acc[i][j] = fmaf(zr[i].x, cr[j].x, acc[i][j]);
                        acc[i][j] = fmaf(zr[i].y, cr[j].y, acc[i][j]);
                        acc[i][j] = fmaf(zr[i].z, cr[j].z, acc[i][j]);
                        acc[i][j] = fmaf(zr[i].w, cr[j].w, acc[i][j]);
                    }
            }
        }

        // chunk epilogue: quantized f32 distance + top-1 (lowest index on ties)
        float cn[NC];
        #pragma unroll
        for (int j = 0; j < NC; ++j) cn[j] = cnorm[nc * TN + j * 32 + tx];

        #pragma unroll
        for (int i = 0; i < NR; ++i) {
            float c1 = 3.0e38f; int ci = 0;
            #pragma unroll
            for (int j = 0; j < NC; ++j) {          // j ascending -> ascending code
                int code = nc * TN + j * 32 + tx;
                float A  = zzr[i] + cn[j];          // fl(zz + cc)
                float dq = A - 2.0f * acc[i][j];    // fl(A - fl(2e)); 2e exact
                if (dq < c1) { c1 = dq; ci = code; }
            }
            #pragma unroll
            for (int off = 1; off < 32; off <<= 1) {
                float o1 = __shfl_xor(c1, off, 32);
                int  oi = __shfl_xor(ci, off, 32);
                if (o1 < c1 || (o1 == c1 && oi < ci)) { c1 = o1; ci = oi; }
            }
            if (c1 < rm1[i] || (c1 == rm1[i] && ci < ridx[i])) { rm1[i] = c1; ridx[i] = ci; }
        }
    }

    if (tx == 0) {
        #pragma unroll
        for (int i = 0; i < NR; ++i) out_idx[row0 + ty * NR + i] = (float)ridx[i];
    }
}

// z_st = fl(z + fl(z_q - z)); grid-strided so partials[2048] matches grid exactly.
__global__ __launch_bounds__(256)
void vq_outputs(const float* __restrict__ z, const float* __restrict__ cb,
                const float* __restrict__ out_idx, float* __restrict__ out,
                double* __restrict__ partials)
{
    __shared__ double sred[4];
    const int tid = threadIdx.x;
    double ls = 0.0;
    #pragma unroll 1
    for (int it = 0; it < 16; ++it) {
        size_t g = ((size_t)blockIdx.x * 16 + it) * 256 + tid;   // float4 index
        int row = (int)(g >> 6);
        int c4  = (int)(g & 63);
        float4 zv = ((const float4*)z)[g];
        int idx = (int)out_idx[row];
        float4 cv = ((const float4*)(cb + (size_t)idx * DIM))[c4];
        float4 o;
        o.x = zv.x + (cv.x - zv.x);
        o.y = zv.y + (cv.y - zv.y);
        o.z = zv.z + (cv.z - zv.z);
        o.w = zv.w + (cv.w - zv.w);
        ((float4*)out)[g] = o;
        float dx = zv.x - cv.x, dy = zv.y - cv.y, dz = zv.z - cv.z, dw = zv.w - cv.w;
        ls += (double)dx * dx + (double)dy * dy + (double)dz * dz + (double)dw * dw;
    }
    #pragma unroll
    for (int off = 32; off > 0; off >>= 1) ls += __shfl_down(ls, off);
    if ((tid & 63) == 0) sred[tid >> 6] = ls;
    __syncthreads();
    if (tid == 0) partials[blockIdx.x] = (sred[0] + sred[1]) + (sred[2] + sred[3]);
}

__global__ void vq_loss_final(const double* __restrict__ partials, float* __restrict__ out_loss) {
    __shared__ double s[256];
    const int tid = threadIdx.x;
    double a = 0.0;
    for (int i = tid; i < 2048; i += 256) a += partials[i];
    s[tid] = a;
    __syncthreads();
    for (int sft = 128; sft > 0; sft >>= 1) {
        if (tid < sft) s[tid] += s[tid + sft];
        __syncthreads();
    }
    if (tid == 0) {
        float mean = (float)(s[0] / (double)((size_t)N_TOK * DIM));
        out_loss[0] = 0.25f * mean + mean;   // commit + codebook, reference op order
    }
}

extern "C" void kernel_launch(void* const* d_in, const int* in_sizes, int n_in,
                              void* d_out, int out_size, void* d_ws, size_t ws_size,
                              hipStream_t stream) {
    const float* z  = (const float*)d_in[0];
    const float* cb = (const float*)d_in[1];
    float* out = (float*)d_out;
    char* ws = (char*)d_ws;

    double* partials = (double*)(ws);                       // 16 KB
    float*  cnorm    = (float*)(ws + 16384);                // 4 KB
    float*  zzg      = (float*)(ws + 20480);                // 512 KB
    float*  cbT      = (float*)(ws + 544768);               // 1 MB (optional)
    const bool useT  = ws_size >= (size_t)(544768 + KC * DIM * 4);

    float* out_idx  = out + (size_t)N_TOK * DIM;
    float* out_loss = out_idx + N_TOK;

    vq_znorm<<<N_TOK / 4, 256, 0, stream>>>(z, zzg);
    vq_cnorm<<<KC / 4, 256, 0, stream>>>(cb, cnorm);
    if (useT) {
        vq_transpose<<<(KC * DIM / 4) / 256, 256, 0, stream>>>(cb, cbT);
        vq_scores<true><<<N_TOK / TM, 256, 0, stream>>>(z, cb, cbT, cnorm, zzg, out_idx);
    } else {
        vq_scores<false><<<N_TOK / TM, 256, 0, stream>>>(z, cb, cb, cnorm, zzg, out_idx);
    }
    vq_outputs<<<2048, 256, 0, stream>>>(z, cb, out_idx, out, partials);
    vq_loss_final<<<1, 256, 0, stream>>>(partials, out_loss);
}